// Round 6
// baseline (279.887 us; speedup 1.0000x reference)
//
#include <hip/hip_runtime.h>
#include <math.h>

// Problem constants (B=2, C=64, CI=32, T=16, H=W=14)
#define S3   3136      // per-channel spatial size = 16*196
#define PB   100352    // per-batch proj elements = 32*3136
#define XB   200704    // per-batch x elements = 64*3136
#define NN   6272      // CI*H*W = spatial attention sequence length
#define MW   7         // spatial m-split (wave-tasks per n-tile)
#define MPW  896       // m per wave-task = NN/MW
#define TGC  49        // temporal gram chunks per batch (128 n each)
#define GRID 512       // persistent blocks; 4 blocks/CU capacity -> 2x margin
#define SPB  464       // spatial blocks; rest (48) do temporal gram

typedef __attribute__((ext_vector_type(8))) short bf16x8;   // 8 bf16 = 4 VGPRs
typedef __attribute__((ext_vector_type(4))) float f32x4;    // MFMA C/D

__device__ inline ushort f2bf(float f) {     // RNE f32 -> bf16
    uint u = __float_as_uint(f);
    return (ushort)((u + 0x7FFFu + ((u >> 16) & 1u)) >> 16);
}

__device__ inline void grid_barrier(int* ctr, int nblk) {
    __syncthreads();
    if (threadIdx.x == 0) {
        __threadfence();                                   // release prior writes
        atomicAdd(ctr, 1);                                 // device-scope
        while (__hip_atomic_load(ctr, __ATOMIC_RELAXED,
                                 __HIP_MEMORY_SCOPE_AGENT) < nblk)
            __builtin_amdgcn_s_sleep(8);
        __threadfence();                                   // acquire others' writes
    }
    __syncthreads();
}

struct Params {
    const float *x;
    const float *W[6];
    const float *bias[6];
    const float *Ww, *bw;
    int    *bar;               // 2 barrier counters (zeroed via memsetAsync)
    ushort *Qb, *Kb, *Vb;      // bf16 spatial (Q/K transposed [n][16], V [t][n])
    float  *Qt, *Kt, *Vt;      // fp32 temporal natural
    float  *Gp, *Pacc, *Pl;
    float  *out;
};

// ---------------------------------------------------------------------------
// One persistent kernel, three phases separated by homemade grid barriers.
// All phase math identical to the verified round-4 kernels.
// ---------------------------------------------------------------------------
__global__ __launch_bounds__(256, 4) void fused_kernel(Params p)
{
    __shared__ __align__(16) char smem[16384];
    const int tid = threadIdx.x;
    const int bid = blockIdx.x;

    // ===================== Phase 1: 6 QKV projections =====================
    {
        int gid = bid * 256 + tid;                 // 131072 threads, 75264 items
        if (gid < 75264) {
            int bs = gid % 6272;
            int yz = gid / 6272;                   // 0..11
            int y = yz >> 1, z = yz & 1;
            int b = (bs >= S3) ? 1 : 0;
            int s = bs - b * S3;

            const float* Wp = p.W[y];
            const float* bp = p.bias[y];

            float a[16];
            #pragma unroll
            for (int oo = 0; oo < 16; ++oo) a[oo] = bp[z * 16 + oo];

            #pragma unroll
            for (int cc = 0; cc < 4; ++cc) {       // c-chunked to cap VGPR
                float xr[16];
                #pragma unroll
                for (int k = 0; k < 16; ++k)
                    xr[k] = p.x[(size_t)b * XB + (size_t)(cc * 16 + k) * S3 + s];
                #pragma unroll
                for (int oo = 0; oo < 16; ++oo) {
                    int o = z * 16 + oo;
                    #pragma unroll
                    for (int k = 0; k < 16; ++k)
                        a[oo] = fmaf(Wp[o * 64 + cc * 16 + k], xr[k], a[oo]);
                }
            }

            if (y < 2) {
                // bf16 transposed [n][16]: o = z*16+2k+h -> t = z*8+k, n = h*S3+s
                const float sc = (y == 0) ? 0.36067376022224085f : 1.0f; // 0.25*log2e
                ushort* ob = (y == 0) ? p.Qb : p.Kb;
                #pragma unroll
                for (int h = 0; h < 2; ++h) {
                    int n = h * S3 + s;
                    uint u0 = f2bf(a[0 + h] * sc)  | ((uint)f2bf(a[2 + h]  * sc) << 16);
                    uint u1 = f2bf(a[4 + h] * sc)  | ((uint)f2bf(a[6 + h]  * sc) << 16);
                    uint u2 = f2bf(a[8 + h] * sc)  | ((uint)f2bf(a[10 + h] * sc) << 16);
                    uint u3 = f2bf(a[12 + h] * sc) | ((uint)f2bf(a[14 + h] * sc) << 16);
                    *(uint4*)(ob + ((size_t)(b * NN + n) * 16 + z * 8)) =
                        make_uint4(u0, u1, u2, u3);
                }
            } else if (y == 2) {
                // bf16 natural [t][n]
                #pragma unroll
                for (int oo = 0; oo < 16; ++oo) {
                    int o = z * 16 + oo;
                    p.Vb[(size_t)(b * 16 + (o >> 1)) * NN + (o & 1) * S3 + s] = f2bf(a[oo]);
                }
            } else {
                float* op = (y == 3) ? p.Qt : (y == 4) ? p.Kt : p.Vt;
                #pragma unroll
                for (int oo = 0; oo < 16; ++oo)
                    op[(size_t)b * PB + (size_t)(z * 16 + oo) * S3 + s] = a[oo];
            }
        }
    }

    grid_barrier(p.bar + 0, GRID);

    // ===================== Phase 2: attention =====================
    if (bid < SPB) {
        // ---- spatial flash attention via bf16 MFMA; wave-task round robin ----
        int wave = __builtin_amdgcn_readfirstlane((int)(tid >> 6));
        int lane = tid & 63;
        int col  = lane & 15;
        int kg   = lane >> 4;
        int gwave = bid * 4 + wave;                // 0..1855
        ushort* myt = (ushort*)(smem + wave * 1280);   // [16 n][32 m] bf16, 80B rows
        const bf16x8 ones = {16256, 16256, 16256, 16256, 16256, 16256, 16256, 16256};
        f32x4 zero4 = {0.f, 0.f, 0.f, 0.f};

        for (int task = gwave; task < 2 * 2744; task += SPB * 4) {
            int b = task / 2744;
            int r = task - b * 2744;
            int ntile = r / 7;
            int w     = r - ntile * 7;
            int nbase = ntile * 16;
            int m0    = w * MPW;

            bf16x8 qf = {0, 0, 0, 0, 0, 0, 0, 0};
            if (kg < 2)
                qf = *(const bf16x8*)(p.Qb + ((size_t)(b * NN + nbase + col) * 16 + kg * 8));

            f32x4 yacc = zero4;
            f32x4 lacc = zero4;

            for (int it = 0; it < MPW / 32; ++it) {
                int mb = m0 + it * 32;
                bf16x8 vf = *(const bf16x8*)(p.Vb + ((size_t)(b * 16 + col) * NN + mb + kg * 8));

                #pragma unroll
                for (int tile = 0; tile < 2; ++tile) {
                    int mt = mb + tile * 16;
                    bf16x8 kf = {0, 0, 0, 0, 0, 0, 0, 0};
                    if (kg < 2)
                        kf = *(const bf16x8*)(p.Kb + ((size_t)(b * NN + mt + col) * 16 + kg * 8));
                    f32x4 st = __builtin_amdgcn_mfma_f32_16x16x32_bf16(kf, qf, zero4, 0, 0, 0);
                    float p0 = __builtin_amdgcn_exp2f(st[0]);
                    float p1 = __builtin_amdgcn_exp2f(st[1]);
                    float p2 = __builtin_amdgcn_exp2f(st[2]);
                    float p3 = __builtin_amdgcn_exp2f(st[3]);
                    uint lo = f2bf(p0) | ((uint)f2bf(p1) << 16);
                    uint hi = f2bf(p2) | ((uint)f2bf(p3) << 16);
                    *(uint2*)(myt + (col * 40 + tile * 16 + kg * 4)) = make_uint2(lo, hi);
                }
                bf16x8 pf = *(bf16x8*)(myt + (col * 40 + kg * 8));
                yacc = __builtin_amdgcn_mfma_f32_16x16x32_bf16(vf, pf, yacc, 0, 0, 0);
                lacc = __builtin_amdgcn_mfma_f32_16x16x32_bf16(ones, pf, lacc, 0, 0, 0);
            }

            #pragma unroll
            for (int r4 = 0; r4 < 4; ++r4) {
                int t = kg * 4 + r4;
                p.Pacc[((size_t)(b * 16 + t) * MW + w) * NN + nbase + col] = yacc[r4];
            }
            if (kg == 0)
                p.Pl[((size_t)b * MW + w) * NN + nbase + col] = lacc[0];
        }
    } else {
        // ---- temporal Gram: 98 chunk-tasks over 48 blocks ----
        float* qs = (float*)smem;          // 2048 floats
        float* ks = qs + 2048;
        for (int c2 = bid - SPB; c2 < 98; c2 += GRID - SPB) {
            int bb = c2 / TGC;
            int ch = c2 - bb * TGC;
            size_t base = (size_t)bb * PB + (size_t)ch * 2048;
            __syncthreads();               // protect LDS reuse across iterations
            for (int i = tid; i < 512; i += 256) {
                ((float4*)qs)[i] = ((const float4*)(p.Qt + base))[i];
                ((float4*)ks)[i] = ((const float4*)(p.Kt + base))[i];
            }
            __syncthreads();
            int t = tid >> 4, s = tid & 15;
            float acc = 0.0f;
            #pragma unroll 8
            for (int n = 0; n < 128; ++n)
                acc = fmaf(qs[n * 16 + t], ks[n * 16 + s], acc);
            p.Gp[(size_t)(bb * TGC + ch) * 256 + tid] = acc;
        }
    }

    grid_barrier(p.bar + 1, GRID);

    // ======= Phase 3: merge + temporal softmax + yt + final proj =======
    if (bid < 392) {
        float* Lsh = (float*)smem;                 // 256
        float* Ash = Lsh + 256;                    // [s2][t2] 16*17 = 272
        float* Wsh = Ash + 272;                    // [c][ci] 64*36 = 2304
        float* Ysh = Wsh + 2304;                   // [ss][ci] 16*36 = 576

        int b  = (bid >= 196) ? 1 : 0;
        int sc = bid - b * 196;                    // s chunk [sc*16, sc*16+16)

        {
            float a = 0.0f;
            for (int c = 0; c < TGC; ++c)
                a += p.Gp[(size_t)(b * TGC + c) * 256 + tid];
            Lsh[tid] = a * 0.25f;
            for (int i = tid; i < 2048; i += 256)
                Wsh[(i >> 5) * 36 + (i & 31)] = p.Ww[i];
        }
        __syncthreads();
        if (tid < 16) {
            int t = tid;
            const float* Lr = &Lsh[t * 16];
            float mx = -1e30f;
            #pragma unroll
            for (int s = 0; s < 16; ++s) mx = fmaxf(mx, Lr[s]);
            float e[16]; float sm = 0.0f;
            #pragma unroll
            for (int s = 0; s < 16; ++s) { e[s] = __expf(Lr[s] - mx); sm += e[s]; }
            float inv = 1.0f / sm;
            #pragma unroll
            for (int s = 0; s < 16; ++s) Ash[s * 17 + t] = e[s] * inv;
        }
        __syncthreads();

        // 512 Y values, 2 per thread
        #pragma unroll
        for (int k = 0; k < 2; ++k) {
            int idx = tid + k * 256;
            int ss = idx & 15;
            int ci = idx >> 4;                     // 0..31
            int s  = sc * 16 + ss;
            int t  = ci >> 1;
            int nn = (ci & 1) * S3 + s;

            float a = 0.0f, l = 0.0f;
            #pragma unroll
            for (int w = 0; w < MW; ++w) {
                a += p.Pacc[((size_t)(b * 16 + t) * MW + w) * NN + nn];
                l += p.Pl[((size_t)b * MW + w) * NN + nn];
            }
            float ys = a / l;

            int t2 = nn & 15;
            const float4* vp = (const float4*)(p.Vt + (size_t)b * PB + (size_t)t * NN + (nn & ~15));
            float4 v0 = vp[0], v1 = vp[1], v2 = vp[2], v3 = vp[3];
            float yt = Ash[0 * 17 + t2] * v0.x;
            yt = fmaf(Ash[1 * 17 + t2],  v0.y, yt); yt = fmaf(Ash[2 * 17 + t2],  v0.z, yt);
            yt = fmaf(Ash[3 * 17 + t2],  v0.w, yt); yt = fmaf(Ash[4 * 17 + t2],  v1.x, yt);
            yt = fmaf(Ash[5 * 17 + t2],  v1.y, yt); yt = fmaf(Ash[6 * 17 + t2],  v1.z, yt);
            yt = fmaf(Ash[7 * 17 + t2],  v1.w, yt); yt = fmaf(Ash[8 * 17 + t2],  v2.x, yt);
            yt = fmaf(Ash[9 * 17 + t2],  v2.y, yt); yt = fmaf(Ash[10 * 17 + t2], v2.z, yt);
            yt = fmaf(Ash[11 * 17 + t2], v2.w, yt); yt = fmaf(Ash[12 * 17 + t2], v3.x, yt);
            yt = fmaf(Ash[13 * 17 + t2], v3.y, yt); yt = fmaf(Ash[14 * 17 + t2], v3.z, yt);
            yt = fmaf(Ash[15 * 17 + t2], v3.w, yt);

            Ysh[ss * 36 + ci] = ys + yt;
        }
        __syncthreads();

        // 64c x 16ss outputs, 4 per thread
        int ss  = tid & 15;
        int cg4 = tid >> 4;
        int s   = sc * 16 + ss;

        float acc[4];
        #pragma unroll
        for (int k = 0; k < 4; ++k) acc[k] = p.bw[cg4 * 4 + k];

        #pragma unroll
        for (int cb = 0; cb < 32; cb += 4) {
            float4 y4 = *(const float4*)&Ysh[ss * 36 + cb];
            #pragma unroll
            for (int k = 0; k < 4; ++k) {
                float4 w4 = *(const float4*)&Wsh[(cg4 * 4 + k) * 36 + cb];
                acc[k] = fmaf(w4.x, y4.x, acc[k]);
                acc[k] = fmaf(w4.y, y4.y, acc[k]);
                acc[k] = fmaf(w4.z, y4.z, acc[k]);
                acc[k] = fmaf(w4.w, y4.w, acc[k]);
            }
        }

        #pragma unroll
        for (int k = 0; k < 4; ++k) {
            int c = cg4 * 4 + k;
            size_t o = (size_t)b * XB + (size_t)c * S3 + s;
            p.out[o] = p.x[o] + acc[k];
        }
    }
}

// ---------------------------------------------------------------------------
extern "C" void kernel_launch(void* const* d_in, const int* in_sizes, int n_in,
                              void* d_out, int out_size, void* d_ws, size_t ws_size,
                              hipStream_t stream)
{
    Params p;
    p.x = (const float*)d_in[0];
    for (int i = 0; i < 6; ++i) {
        p.W[i]    = (const float*)d_in[1 + 2 * i];
        p.bias[i] = (const float*)d_in[2 + 2 * i];
    }
    p.Ww = (const float*)d_in[13];
    p.bw = (const float*)d_in[14];

    // workspace layout (float units)
    float* ws = (float*)d_ws;
    p.bar = (int*)ws;                // 4 ints (only 2 used), 16B-aligned pad
    p.Qb  = (ushort*)(ws + 4);       // 200704 bf16 = 100352 fl
    p.Kb  = (ushort*)(ws + 100356);
    p.Vb  = (ushort*)(ws + 200708);
    p.Qt  = ws + 301060;             // 200704
    p.Kt  = ws + 501764;
    p.Vt  = ws + 702468;
    p.Gp  = ws + 903172;             // 2*49*256 = 25088
    p.Pacc = ws + 928260;            // 2*16*7*6272 = 1404928
    p.Pl   = ws + 2333188;           // 2*7*6272 = 87808
    p.out  = (float*)d_out;

    hipMemsetAsync(p.bar, 0, 2 * sizeof(int), stream);
    fused_kernel<<<GRID, 256, 0, stream>>>(p);
}

// Round 7
// 149.836 us; speedup vs baseline: 1.8680x; 1.8680x over previous
//
#include <hip/hip_runtime.h>
#include <math.h>

// Problem constants (B=2, C=64, CI=32, T=16, H=W=14)
#define S3   3136      // per-channel spatial size = 16*196
#define PB   100352    // per-batch proj elements = 32*3136
#define XB   200704    // per-batch x elements = 64*3136
#define NN   6272      // CI*H*W = spatial attention sequence length

typedef __attribute__((ext_vector_type(8))) short bf16x8;   // 8 bf16 = 4 VGPRs
typedef __attribute__((ext_vector_type(4))) float f32x4;    // MFMA C/D

__device__ inline ushort f2bf(float f) {     // RNE f32 -> bf16
    uint u = __float_as_uint(f);
    return (ushort)((u + 0x7FFFu + ((u >> 16) & 1u)) >> 16);
}

// ---------------------------------------------------------------------------
// Kernel 1: all 6 QKV projections, 2x o-split (verified R4). Also zeroes the
// gram completion counters (workspace is poisoned 0xAA before every call).
// ---------------------------------------------------------------------------
__global__ __launch_bounds__(256) void proj_kernel(
    const float* __restrict__ x,
    const float* __restrict__ W0, const float* __restrict__ b0,
    const float* __restrict__ W1, const float* __restrict__ b1,
    const float* __restrict__ W2, const float* __restrict__ b2,
    const float* __restrict__ W3, const float* __restrict__ b3,
    const float* __restrict__ W4, const float* __restrict__ b4,
    const float* __restrict__ W5, const float* __restrict__ b5,
    ushort* __restrict__ Qb, ushort* __restrict__ Kb, ushort* __restrict__ Vb,
    float* __restrict__ Qt, float* __restrict__ Kt, float* __restrict__ Vt,
    int* __restrict__ cnt)
{
    if (blockIdx.x == 0 && blockIdx.y == 0 && blockIdx.z == 0 && threadIdx.x < 2)
        cnt[threadIdx.x] = 0;

    const float* Wp; const float* bp;
    switch (blockIdx.y) {
        case 0:  Wp = W0; bp = b0; break;
        case 1:  Wp = W1; bp = b1; break;
        case 2:  Wp = W2; bp = b2; break;
        case 3:  Wp = W3; bp = b3; break;
        case 4:  Wp = W4; bp = b4; break;
        default: Wp = W5; bp = b5; break;
    }
    int z = blockIdx.z;               // o in [z*16, z*16+16)

    int gid = blockIdx.x * 256 + threadIdx.x;
    if (gid >= 2 * S3) return;
    int b = (gid >= S3) ? 1 : 0;
    int s = gid - b * S3;

    float xr[64];
    #pragma unroll
    for (int c = 0; c < 64; ++c) xr[c] = x[(size_t)b * XB + (size_t)c * S3 + s];

    float a[16];
    #pragma unroll
    for (int oo = 0; oo < 16; ++oo) {
        int o = z * 16 + oo;
        float acc = bp[o];
        #pragma unroll
        for (int c = 0; c < 64; ++c) acc = fmaf(Wp[o * 64 + c], xr[c], acc);
        a[oo] = acc;
    }

    if (blockIdx.y < 2) {
        // bf16 transposed [n][16]: o = z*16+2k+h -> t = z*8+k, n = h*S3+s
        const float sc = (blockIdx.y == 0) ? 0.36067376022224085f : 1.0f; // 0.25*log2e
        ushort* ob = (blockIdx.y == 0) ? Qb : Kb;
        #pragma unroll
        for (int h = 0; h < 2; ++h) {
            int n = h * S3 + s;
            uint u0 = f2bf(a[0 + h] * sc)  | ((uint)f2bf(a[2 + h]  * sc) << 16);
            uint u1 = f2bf(a[4 + h] * sc)  | ((uint)f2bf(a[6 + h]  * sc) << 16);
            uint u2 = f2bf(a[8 + h] * sc)  | ((uint)f2bf(a[10 + h] * sc) << 16);
            uint u3 = f2bf(a[12 + h] * sc) | ((uint)f2bf(a[14 + h] * sc) << 16);
            *(uint4*)(ob + ((size_t)(b * NN + n) * 16 + z * 8)) = make_uint4(u0, u1, u2, u3);
        }
    } else if (blockIdx.y == 2) {
        // bf16 natural [t][n]
        #pragma unroll
        for (int oo = 0; oo < 16; ++oo) {
            int o = z * 16 + oo;
            Vb[(size_t)(b * 16 + (o >> 1)) * NN + (o & 1) * S3 + s] = f2bf(a[oo]);
        }
    } else {
        float* op = (blockIdx.y == 3) ? Qt : (blockIdx.y == 4) ? Kt : Vt;
        #pragma unroll
        for (int oo = 0; oo < 16; ++oo)
            op[(size_t)b * PB + (size_t)(z * 16 + oo) * S3 + s] = a[oo];
    }
}

// ---------------------------------------------------------------------------
// Kernel 2 (heterogeneous, 816 blocks):
//  blocks 0..783: spatial flash attention, one FULL n-tile per block:
//    4 waves x m-quarters of 1568 (49 MFMA iters), then in-block LDS merge
//    -> Y (= ys, natural flat layout) directly. No Pacc/Pl round trip.
//  blocks 784..815: temporal Gram partials (392-n chunks); the last-arriving
//    block per batch reduces 16 partials + softmax -> At. (atomic counter +
//    threadfence pattern, validated in R6.)
// ---------------------------------------------------------------------------
__global__ __launch_bounds__(256, 4) void attn_kernel(
    const ushort* __restrict__ Qb, const ushort* __restrict__ Kb,
    const ushort* __restrict__ Vb, const float* __restrict__ Qt,
    const float* __restrict__ Kt,
    float* __restrict__ Y, float* __restrict__ Gpart,
    float* __restrict__ At, int* __restrict__ cnt)
{
    __shared__ __align__(16) char smem[16384];
    const int tid = threadIdx.x;
    const int bid = blockIdx.x;

    if (bid < 784) {
        // ------------------- spatial flash attention -------------------
        ushort* ptile = (ushort*)smem;                 // 4 waves x 1280 B
        float*  smY   = (float*)(smem + 5120);         // [4][16][17] = 4352 B
        float*  sml   = (float*)(smem + 9472);         // [4][16]     = 256 B

        int wave = __builtin_amdgcn_readfirstlane((int)(tid >> 6));
        int lane = tid & 63;
        int col  = lane & 15;
        int kg   = lane >> 4;
        int b    = (bid >= 392) ? 1 : 0;
        int ntile = bid - b * 392;
        int nbase = ntile * 16;
        int m0    = wave * 1568;

        bf16x8 qf = {0, 0, 0, 0, 0, 0, 0, 0};
        if (kg < 2)
            qf = *(const bf16x8*)(Qb + ((size_t)(b * NN + nbase + col) * 16 + kg * 8));

        const bf16x8 ones = {16256, 16256, 16256, 16256, 16256, 16256, 16256, 16256};
        f32x4 zero4 = {0.f, 0.f, 0.f, 0.f};
        f32x4 yacc  = zero4;
        f32x4 lacc  = zero4;

        ushort* myt = ptile + wave * 640;              // [16 n][32 m] bf16, 80B rows

        for (int it = 0; it < 49; ++it) {
            int mb = m0 + it * 32;
            bf16x8 vf = *(const bf16x8*)(Vb + ((size_t)(b * 16 + col) * NN + mb + kg * 8));

            #pragma unroll
            for (int tile = 0; tile < 2; ++tile) {
                int mt = mb + tile * 16;
                bf16x8 kf = {0, 0, 0, 0, 0, 0, 0, 0};
                if (kg < 2)
                    kf = *(const bf16x8*)(Kb + ((size_t)(b * NN + mt + col) * 16 + kg * 8));
                f32x4 st = __builtin_amdgcn_mfma_f32_16x16x32_bf16(kf, qf, zero4, 0, 0, 0);
                float p0 = __builtin_amdgcn_exp2f(st[0]);
                float p1 = __builtin_amdgcn_exp2f(st[1]);
                float p2 = __builtin_amdgcn_exp2f(st[2]);
                float p3 = __builtin_amdgcn_exp2f(st[3]);
                uint lo = f2bf(p0) | ((uint)f2bf(p1) << 16);
                uint hi = f2bf(p2) | ((uint)f2bf(p3) << 16);
                *(uint2*)(myt + (col * 40 + tile * 16 + kg * 4)) = make_uint2(lo, hi);
            }
            bf16x8 pf = *(bf16x8*)(myt + (col * 40 + kg * 8));
            yacc = __builtin_amdgcn_mfma_f32_16x16x32_bf16(vf, pf, yacc, 0, 0, 0);
            lacc = __builtin_amdgcn_mfma_f32_16x16x32_bf16(ones, pf, lacc, 0, 0, 0);
        }

        // in-block merge of the 4 m-quarter partials
        #pragma unroll
        for (int r = 0; r < 4; ++r)
            smY[(wave * 16 + kg * 4 + r) * 17 + col] = yacc[r];
        if (kg == 0) sml[wave * 16 + col] = lacc[0];
        __syncthreads();

        int t  = tid >> 4;
        int nn = tid & 15;
        float a = smY[(0 * 16 + t) * 17 + nn] + smY[(1 * 16 + t) * 17 + nn]
                + smY[(2 * 16 + t) * 17 + nn] + smY[(3 * 16 + t) * 17 + nn];
        float l = sml[0 * 16 + nn] + sml[1 * 16 + nn]
                + sml[2 * 16 + nn] + sml[3 * 16 + nn];
        Y[(size_t)b * PB + (size_t)t * NN + nbase + nn] = a / l;
    } else {
        // ------------------- temporal Gram + last-block softmax -------------------
        float* qs = (float*)smem;                      // 1568 floats
        float* ks = qs + 1568;
        int*   flag = (int*)(smem + 16000);

        int gb = bid - 784;                            // 0..31
        int b  = gb >> 4;
        int ch = gb & 15;                              // 392-n chunk
        int t  = tid >> 4, s2 = tid & 15;

        float acc = 0.0f;
        for (int sub = 0; sub < 4; ++sub) {
            size_t base = (size_t)b * PB + (size_t)(ch * 392 + sub * 98) * 16;
            __syncthreads();
            for (int i = tid; i < 392; i += 256) {     // 392 float4 = 1568 floats
                ((float4*)qs)[i] = ((const float4*)(Qt + base))[i];
                ((float4*)ks)[i] = ((const float4*)(Kt + base))[i];
            }
            __syncthreads();
            #pragma unroll 7
            for (int n = 0; n < 98; ++n)
                acc = fmaf(qs[n * 16 + t], ks[n * 16 + s2], acc);
        }
        Gpart[(size_t)(b * 16 + ch) * 256 + tid] = acc;

        __threadfence();                               // release partial (all threads)
        __syncthreads();
        if (tid == 0) {
            int old = atomicAdd(cnt + b, 1);           // device-scope
            *flag = (old == 15);
        }
        __syncthreads();
        if (*flag) {
            __threadfence();                           // acquire others' partials
            float a = 0.0f;
            #pragma unroll
            for (int c = 0; c < 16; ++c)
                a += Gpart[(size_t)(b * 16 + c) * 256 + tid];
            qs[tid] = a * 0.25f;                       // logits
            __syncthreads();
            if (tid < 16) {
                const float* Lr = &qs[tid * 16];
                float mx = -1e30f;
                #pragma unroll
                for (int s = 0; s < 16; ++s) mx = fmaxf(mx, Lr[s]);
                float e[16]; float sm = 0.0f;
                #pragma unroll
                for (int s = 0; s < 16; ++s) { e[s] = __expf(Lr[s] - mx); sm += e[s]; }
                float inv = 1.0f / sm;
                #pragma unroll
                for (int s = 0; s < 16; ++s) At[b * 256 + tid * 16 + s] = e[s] * inv;
            }
        }
    }
}

// ---------------------------------------------------------------------------
// Kernel 3: yt add + output projection + residual. Grid (196, 2).
//  A: load At -> Ash (transposed), stage Ww -> Wsh.
//  B: Ysh[ss][ci] = Y(b,ci,s) + yt.
//  C: out[b,c,s] = x + bw[c] + sum_ci Wsh[c][ci]*Ysh[ss][ci]
//     channel map c = k*16+cg4 -> Wsh bank step 4 (2-way, free).
// ---------------------------------------------------------------------------
__global__ __launch_bounds__(256) void merge_final(
    const float* __restrict__ Y, const float* __restrict__ At,
    const float* __restrict__ Vt, const float* __restrict__ x,
    const float* __restrict__ Ww, const float* __restrict__ bw,
    float* __restrict__ out)
{
    __shared__ float Ash[16 * 17];   // [s2][t2]
    __shared__ float Wsh[64 * 36];   // [c][ci]
    __shared__ float Ysh[16 * 36];   // [ss][ci]

    int b  = blockIdx.y;
    int sc = blockIdx.x;             // s chunk [sc*16, sc*16+16)
    int tid = threadIdx.x;

    {
        int s2 = tid >> 4, t2 = tid & 15;
        Ash[s2 * 17 + t2] = At[b * 256 + t2 * 16 + s2];
        for (int i = tid; i < 2048; i += 256)
            Wsh[(i >> 5) * 36 + (i & 31)] = Ww[i];
    }
    __syncthreads();

    // phase B: 512 Y values, 2 per thread
    #pragma unroll
    for (int k = 0; k < 2; ++k) {
        int idx = tid + k * 256;
        int ss = idx & 15;
        int ci = idx >> 4;                     // 0..31
        int s  = sc * 16 + ss;
        int t  = ci >> 1;
        int nn = (ci & 1) * S3 + s;

        float ys = Y[(size_t)b * PB + (size_t)ci * S3 + s];

        int t2 = nn & 15;
        const float4* vp = (const float4*)(Vt + (size_t)b * PB + (size_t)t * NN + (nn & ~15));
        float4 v0 = vp[0], v1 = vp[1], v2 = vp[2], v3 = vp[3];
        float yt = Ash[0 * 17 + t2] * v0.x;
        yt = fmaf(Ash[1 * 17 + t2],  v0.y, yt); yt = fmaf(Ash[2 * 17 + t2],  v0.z, yt);
        yt = fmaf(Ash[3 * 17 + t2],  v0.w, yt); yt = fmaf(Ash[4 * 17 + t2],  v1.x, yt);
        yt = fmaf(Ash[5 * 17 + t2],  v1.y, yt); yt = fmaf(Ash[6 * 17 + t2],  v1.z, yt);
        yt = fmaf(Ash[7 * 17 + t2],  v1.w, yt); yt = fmaf(Ash[8 * 17 + t2],  v2.x, yt);
        yt = fmaf(Ash[9 * 17 + t2],  v2.y, yt); yt = fmaf(Ash[10 * 17 + t2], v2.z, yt);
        yt = fmaf(Ash[11 * 17 + t2], v2.w, yt); yt = fmaf(Ash[12 * 17 + t2], v3.x, yt);
        yt = fmaf(Ash[13 * 17 + t2], v3.y, yt); yt = fmaf(Ash[14 * 17 + t2], v3.z, yt);
        yt = fmaf(Ash[15 * 17 + t2], v3.w, yt);

        Ysh[ss * 36 + ci] = ys + yt;
    }
    __syncthreads();

    // phase C: 64c x 16ss outputs, 4 per thread; c = k*16 + cg4
    int ss  = tid & 15;
    int cg4 = tid >> 4;
    int s   = sc * 16 + ss;

    float acc[4];
    #pragma unroll
    for (int k = 0; k < 4; ++k) acc[k] = bw[k * 16 + cg4];

    #pragma unroll
    for (int cb = 0; cb < 32; cb += 4) {
        float4 y4 = *(const float4*)&Ysh[ss * 36 + cb];
        #pragma unroll
        for (int k = 0; k < 4; ++k) {
            float4 w4 = *(const float4*)&Wsh[(k * 16 + cg4) * 36 + cb];
            acc[k] = fmaf(w4.x, y4.x, acc[k]);
            acc[k] = fmaf(w4.y, y4.y, acc[k]);
            acc[k] = fmaf(w4.z, y4.z, acc[k]);
            acc[k] = fmaf(w4.w, y4.w, acc[k]);
        }
    }

    #pragma unroll
    for (int k = 0; k < 4; ++k) {
        int c = k * 16 + cg4;
        size_t o = (size_t)b * XB + (size_t)c * S3 + s;
        out[o] = x[o] + acc[k];
    }
}

// ---------------------------------------------------------------------------
extern "C" void kernel_launch(void* const* d_in, const int* in_sizes, int n_in,
                              void* d_out, int out_size, void* d_ws, size_t ws_size,
                              hipStream_t stream)
{
    const float* x   = (const float*)d_in[0];
    const float* Wqs = (const float*)d_in[1];  const float* bqs = (const float*)d_in[2];
    const float* Wks = (const float*)d_in[3];  const float* bks = (const float*)d_in[4];
    const float* Wvs = (const float*)d_in[5];  const float* bvs = (const float*)d_in[6];
    const float* Wqt = (const float*)d_in[7];  const float* bqt = (const float*)d_in[8];
    const float* Wkt = (const float*)d_in[9];  const float* bkt = (const float*)d_in[10];
    const float* Wvt = (const float*)d_in[11]; const float* bvt = (const float*)d_in[12];
    const float* Ww  = (const float*)d_in[13]; const float* bw  = (const float*)d_in[14];

    // workspace layout (float units); ~4.5 MB
    float* ws = (float*)d_ws;
    int*    cnt = (int*)ws;            // 2 counters (+pad to 4)
    ushort* Qb  = (ushort*)(ws + 4);   // 200704 bf16 = 100352 fl
    ushort* Kb  = (ushort*)(ws + 100356);
    ushort* Vb  = (ushort*)(ws + 200708);
    float* Qt   = ws + 301060;         // 200704
    float* Kt   = ws + 501764;
    float* Vt   = ws + 702468;
    float* Y    = ws + 903172;         // 200704
    float* Gpart = ws + 1103876;       // 2*16*256 = 8192
    float* At    = ws + 1112068;       // 512

    proj_kernel<<<dim3(25, 6, 2), 256, 0, stream>>>(
        x, Wqs, bqs, Wks, bks, Wvs, bvs, Wqt, bqt, Wkt, bkt, Wvt, bvt,
        Qb, Kb, Vb, Qt, Kt, Vt, cnt);

    attn_kernel<<<816, 256, 0, stream>>>(Qb, Kb, Vb, Qt, Kt, Y, Gpart, At, cnt);

    merge_final<<<dim3(196, 2), 256, 0, stream>>>(
        Y, At, Vt, x, Ww, bw, (float*)d_out);
}

// Round 8
// 149.116 us; speedup vs baseline: 1.8770x; 1.0048x over previous
//
#include <hip/hip_runtime.h>
#include <math.h>

// Problem constants (B=2, C=64, CI=32, T=16, H=W=14)
#define S3   3136      // per-channel spatial size = 16*196
#define PB   100352    // per-batch proj elements = 32*3136
#define XB   200704    // per-batch x elements = 64*3136
#define NN   6272      // CI*H*W = spatial attention sequence length

typedef __attribute__((ext_vector_type(8))) short bf16x8;   // 8 bf16 = 4 VGPRs
typedef __attribute__((ext_vector_type(4))) float f32x4;    // MFMA C/D

__device__ inline ushort f2bf(float f) {     // RNE f32 -> bf16
    uint u = __float_as_uint(f);
    return (ushort)((u + 0x7FFFu + ((u >> 16) & 1u)) >> 16);
}

// ---------------------------------------------------------------------------
// Kernel 1: all 6 QKV projections, 2x o-split (verified R4/R7). Also zeroes
// the gram completion counters.
// ---------------------------------------------------------------------------
__global__ __launch_bounds__(256) void proj_kernel(
    const float* __restrict__ x,
    const float* __restrict__ W0, const float* __restrict__ b0,
    const float* __restrict__ W1, const float* __restrict__ b1,
    const float* __restrict__ W2, const float* __restrict__ b2,
    const float* __restrict__ W3, const float* __restrict__ b3,
    const float* __restrict__ W4, const float* __restrict__ b4,
    const float* __restrict__ W5, const float* __restrict__ b5,
    ushort* __restrict__ Qb, ushort* __restrict__ Kb, ushort* __restrict__ Vb,
    float* __restrict__ Qt, float* __restrict__ Kt, float* __restrict__ Vt,
    int* __restrict__ cnt)
{
    if (blockIdx.x == 0 && blockIdx.y == 0 && blockIdx.z == 0 && threadIdx.x < 2)
        cnt[threadIdx.x] = 0;

    const float* Wp; const float* bp;
    switch (blockIdx.y) {
        case 0:  Wp = W0; bp = b0; break;
        case 1:  Wp = W1; bp = b1; break;
        case 2:  Wp = W2; bp = b2; break;
        case 3:  Wp = W3; bp = b3; break;
        case 4:  Wp = W4; bp = b4; break;
        default: Wp = W5; bp = b5; break;
    }
    int z = blockIdx.z;               // o in [z*16, z*16+16)

    int gid = blockIdx.x * 256 + threadIdx.x;
    if (gid >= 2 * S3) return;
    int b = (gid >= S3) ? 1 : 0;
    int s = gid - b * S3;

    float xr[64];
    #pragma unroll
    for (int c = 0; c < 64; ++c) xr[c] = x[(size_t)b * XB + (size_t)c * S3 + s];

    float a[16];
    #pragma unroll
    for (int oo = 0; oo < 16; ++oo) {
        int o = z * 16 + oo;
        float acc = bp[o];
        #pragma unroll
        for (int c = 0; c < 64; ++c) acc = fmaf(Wp[o * 64 + c], xr[c], acc);
        a[oo] = acc;
    }

    if (blockIdx.y < 2) {
        // bf16 transposed [n][16]: o = z*16+2k+h -> t = z*8+k, n = h*S3+s
        const float sc = (blockIdx.y == 0) ? 0.36067376022224085f : 1.0f; // 0.25*log2e
        ushort* ob = (blockIdx.y == 0) ? Qb : Kb;
        #pragma unroll
        for (int h = 0; h < 2; ++h) {
            int n = h * S3 + s;
            uint u0 = f2bf(a[0 + h] * sc)  | ((uint)f2bf(a[2 + h]  * sc) << 16);
            uint u1 = f2bf(a[4 + h] * sc)  | ((uint)f2bf(a[6 + h]  * sc) << 16);
            uint u2 = f2bf(a[8 + h] * sc)  | ((uint)f2bf(a[10 + h] * sc) << 16);
            uint u3 = f2bf(a[12 + h] * sc) | ((uint)f2bf(a[14 + h] * sc) << 16);
            *(uint4*)(ob + ((size_t)(b * NN + n) * 16 + z * 8)) = make_uint4(u0, u1, u2, u3);
        }
    } else if (blockIdx.y == 2) {
        // bf16 natural [t][n]
        #pragma unroll
        for (int oo = 0; oo < 16; ++oo) {
            int o = z * 16 + oo;
            Vb[(size_t)(b * 16 + (o >> 1)) * NN + (o & 1) * S3 + s] = f2bf(a[oo]);
        }
    } else {
        float* op = (blockIdx.y == 3) ? Qt : (blockIdx.y == 4) ? Kt : Vt;
        #pragma unroll
        for (int oo = 0; oo < 16; ++oo)
            op[(size_t)b * PB + (size_t)(z * 16 + oo) * S3 + s] = a[oo];
    }
}

// ---------------------------------------------------------------------------
// Kernel 2 (heterogeneous, 816 blocks x 512 threads):
//  blocks 0..783: spatial flash attention, one n-tile per block, 8 waves
//    each covering 784 m (24 full 32-m iters + 16-m tail). Double-buffered
//    per-wave P tile; in-block LDS merge -> Y directly.
//  blocks 784..815: temporal Gram partials (392-n chunks); last-arriving
//    block per batch reduces + softmax -> At (atomic counter, verified R7).
// ---------------------------------------------------------------------------
__global__ __launch_bounds__(512, 4) void attn_kernel(
    const ushort* __restrict__ Qb, const ushort* __restrict__ Kb,
    const ushort* __restrict__ Vb, const float* __restrict__ Qt,
    const float* __restrict__ Kt,
    float* __restrict__ Y, float* __restrict__ Gpart,
    float* __restrict__ At, int* __restrict__ cnt)
{
    __shared__ __align__(16) char smem[30208];
    const int tid = threadIdx.x;
    const int bid = blockIdx.x;

    if (bid < 784) {
        // ------------------- spatial flash attention -------------------
        ushort* ptile = (ushort*)smem;                 // 8 waves x 2 bufs x 640 ushorts
        float*  smY   = (float*)(smem + 20480);        // [8][16][17] = 8704 B
        float*  sml   = (float*)(smem + 29184);        // [8][16]     = 512 B

        int wave = __builtin_amdgcn_readfirstlane((int)(tid >> 6));
        int lane = tid & 63;
        int col  = lane & 15;
        int kg   = lane >> 4;
        int b    = (bid >= 392) ? 1 : 0;
        int ntile = bid - b * 392;
        int nbase = ntile * 16;
        int m0    = wave * 784;

        bf16x8 qf = {0, 0, 0, 0, 0, 0, 0, 0};
        if (kg < 2)
            qf = *(const bf16x8*)(Qb + ((size_t)(b * NN + nbase + col) * 16 + kg * 8));

        const bf16x8 ones = {16256, 16256, 16256, 16256, 16256, 16256, 16256, 16256};
        f32x4 zero4 = {0.f, 0.f, 0.f, 0.f};
        f32x4 yacc  = zero4;
        f32x4 lacc  = zero4;

        ushort* myt = ptile + wave * 1280;             // 2 buffers of 640

        const ushort* Vrow = Vb + ((size_t)(b * 16 + col) * NN);
        const ushort* Krow = Kb + ((size_t)b * NN) * 16;

        #pragma unroll 2
        for (int it = 0; it < 24; ++it) {
            ushort* buf = myt + (it & 1) * 640;
            int mb = m0 + it * 32;
            bf16x8 vf = *(const bf16x8*)(Vrow + mb + kg * 8);

            #pragma unroll
            for (int tile = 0; tile < 2; ++tile) {
                int mt = mb + tile * 16;
                bf16x8 kf = {0, 0, 0, 0, 0, 0, 0, 0};
                if (kg < 2)
                    kf = *(const bf16x8*)(Krow + (size_t)(mt + col) * 16 + kg * 8);
                f32x4 st = __builtin_amdgcn_mfma_f32_16x16x32_bf16(kf, qf, zero4, 0, 0, 0);
                float p0 = __builtin_amdgcn_exp2f(st[0]);
                float p1 = __builtin_amdgcn_exp2f(st[1]);
                float p2 = __builtin_amdgcn_exp2f(st[2]);
                float p3 = __builtin_amdgcn_exp2f(st[3]);
                // truncation pack (P >= 0, error < 2^-8 relative)
                uint lo = (__float_as_uint(p0) >> 16) | (__float_as_uint(p1) & 0xFFFF0000u);
                uint hi = (__float_as_uint(p2) >> 16) | (__float_as_uint(p3) & 0xFFFF0000u);
                *(uint2*)(buf + (col * 40 + tile * 16 + kg * 4)) = make_uint2(lo, hi);
            }
            bf16x8 pf = *(bf16x8*)(buf + (col * 40 + kg * 8));
            yacc = __builtin_amdgcn_mfma_f32_16x16x32_bf16(vf, pf, yacc, 0, 0, 0);
            lacc = __builtin_amdgcn_mfma_f32_16x16x32_bf16(ones, pf, lacc, 0, 0, 0);
        }

        // ---- 16-m tail (m = m0+768 .. m0+783), kg>=2 fragments zeroed ----
        {
            int mb = m0 + 768;
            bf16x8 vf = {0, 0, 0, 0, 0, 0, 0, 0};
            bf16x8 kf = {0, 0, 0, 0, 0, 0, 0, 0};
            if (kg < 2) {
                vf = *(const bf16x8*)(Vrow + mb + kg * 8);
                kf = *(const bf16x8*)(Krow + (size_t)(mb + col) * 16 + kg * 8);
            }
            f32x4 st = __builtin_amdgcn_mfma_f32_16x16x32_bf16(kf, qf, zero4, 0, 0, 0);
            float p0 = __builtin_amdgcn_exp2f(st[0]);
            float p1 = __builtin_amdgcn_exp2f(st[1]);
            float p2 = __builtin_amdgcn_exp2f(st[2]);
            float p3 = __builtin_amdgcn_exp2f(st[3]);
            uint lo = (__float_as_uint(p0) >> 16) | (__float_as_uint(p1) & 0xFFFF0000u);
            uint hi = (__float_as_uint(p2) >> 16) | (__float_as_uint(p3) & 0xFFFF0000u);
            *(uint2*)(myt + (col * 40 + kg * 4)) = make_uint2(lo, hi);
            bf16x8 pf = {0, 0, 0, 0, 0, 0, 0, 0};
            if (kg < 2) pf = *(bf16x8*)(myt + (col * 40 + kg * 8));
            yacc = __builtin_amdgcn_mfma_f32_16x16x32_bf16(vf, pf, yacc, 0, 0, 0);
            lacc = __builtin_amdgcn_mfma_f32_16x16x32_bf16(ones, pf, lacc, 0, 0, 0);
        }

        // in-block merge of the 8 m-chunk partials
        #pragma unroll
        for (int r = 0; r < 4; ++r)
            smY[(wave * 16 + kg * 4 + r) * 17 + col] = yacc[r];
        if (kg == 0) sml[wave * 16 + col] = lacc[0];
        __syncthreads();

        if (tid < 256) {
            int t  = tid >> 4;
            int nn = tid & 15;
            float a = 0.0f, l = 0.0f;
            #pragma unroll
            for (int w = 0; w < 8; ++w) {
                a += smY[(w * 16 + t) * 17 + nn];
                l += sml[w * 16 + nn];
            }
            Y[(size_t)b * PB + (size_t)t * NN + nbase + nn] = a / l;
        }
    } else {
        // ------------------- temporal Gram + last-block softmax -------------------
        float* qs = (float*)smem;                      // 1568 floats
        float* ks = qs + 1568;
        int*   flag = (int*)(smem + 30000);

        int gb = bid - 784;                            // 0..31
        int b  = gb >> 4;
        int ch = gb & 15;                              // 392-n chunk
        int t  = tid >> 4, s2 = tid & 15;

        float acc = 0.0f;
        for (int sub = 0; sub < 4; ++sub) {
            size_t base = (size_t)b * PB + (size_t)(ch * 392 + sub * 98) * 16;
            __syncthreads();
            for (int i = tid; i < 392; i += 512) {     // 392 float4 = 1568 floats
                ((float4*)qs)[i] = ((const float4*)(Qt + base))[i];
                ((float4*)ks)[i] = ((const float4*)(Kt + base))[i];
            }
            __syncthreads();
            if (tid < 256) {
                #pragma unroll 7
                for (int n = 0; n < 98; ++n)
                    acc = fmaf(qs[n * 16 + t], ks[n * 16 + s2], acc);
            }
        }
        if (tid < 256)
            Gpart[(size_t)(b * 16 + ch) * 256 + tid] = acc;

        __threadfence();                               // release partial
        __syncthreads();
        if (tid == 0) {
            int old = atomicAdd(cnt + b, 1);           // device-scope
            *flag = (old == 15);
        }
        __syncthreads();
        if (*flag) {
            __threadfence();                           // acquire others' partials
            if (tid < 256) {
                float a = 0.0f;
                #pragma unroll
                for (int c = 0; c < 16; ++c)
                    a += Gpart[(size_t)(b * 16 + c) * 256 + tid];
                qs[tid] = a * 0.25f;                   // logits
            }
            __syncthreads();
            if (tid < 16) {
                const float* Lr = &qs[tid * 16];
                float mx = -1e30f;
                #pragma unroll
                for (int s = 0; s < 16; ++s) mx = fmaxf(mx, Lr[s]);
                float e[16]; float sm = 0.0f;
                #pragma unroll
                for (int s = 0; s < 16; ++s) { e[s] = __expf(Lr[s] - mx); sm += e[s]; }
                float inv = 1.0f / sm;
                #pragma unroll
                for (int s = 0; s < 16; ++s) At[b * 256 + tid * 16 + s] = e[s] * inv;
            }
        }
    }
}

// ---------------------------------------------------------------------------
// Kernel 3: yt add + output projection + residual. Grid (196, 2). (verified R7)
// ---------------------------------------------------------------------------
__global__ __launch_bounds__(256) void merge_final(
    const float* __restrict__ Y, const float* __restrict__ At,
    const float* __restrict__ Vt, const float* __restrict__ x,
    const float* __restrict__ Ww, const float* __restrict__ bw,
    float* __restrict__ out)
{
    __shared__ float Ash[16 * 17];   // [s2][t2]
    __shared__ float Wsh[64 * 36];   // [c][ci]
    __shared__ float Ysh[16 * 36];   // [ss][ci]

    int b  = blockIdx.y;
    int sc = blockIdx.x;             // s chunk [sc*16, sc*16+16)
    int tid = threadIdx.x;

    {
        int s2 = tid >> 4, t2 = tid & 15;
        Ash[s2 * 17 + t2] = At[b * 256 + t2 * 16 + s2];
        for (int i = tid; i < 2048; i += 256)
            Wsh[(i >> 5) * 36 + (i & 31)] = Ww[i];
    }
    __syncthreads();

    // phase B: 512 Y values, 2 per thread
    #pragma unroll
    for (int k = 0; k < 2; ++k) {
        int idx = tid + k * 256;
        int ss = idx & 15;
        int ci = idx >> 4;                     // 0..31
        int s  = sc * 16 + ss;
        int t  = ci >> 1;
        int nn = (ci & 1) * S3 + s;

        float ys = Y[(size_t)b * PB + (size_t)ci * S3 + s];

        int t2 = nn & 15;
        const float4* vp = (const float4*)(Vt + (size_t)b * PB + (size_t)t * NN + (nn & ~15));
        float4 v0 = vp[0], v1 = vp[1], v2 = vp[2], v3 = vp[3];
        float yt = Ash[0 * 17 + t2] * v0.x;
        yt = fmaf(Ash[1 * 17 + t2],  v0.y, yt); yt = fmaf(Ash[2 * 17 + t2],  v0.z, yt);
        yt = fmaf(Ash[3 * 17 + t2],  v0.w, yt); yt = fmaf(Ash[4 * 17 + t2],  v1.x, yt);
        yt = fmaf(Ash[5 * 17 + t2],  v1.y, yt); yt = fmaf(Ash[6 * 17 + t2],  v1.z, yt);
        yt = fmaf(Ash[7 * 17 + t2],  v1.w, yt); yt = fmaf(Ash[8 * 17 + t2],  v2.x, yt);
        yt = fmaf(Ash[9 * 17 + t2],  v2.y, yt); yt = fmaf(Ash[10 * 17 + t2], v2.z, yt);
        yt = fmaf(Ash[11 * 17 + t2], v2.w, yt); yt = fmaf(Ash[12 * 17 + t2], v3.x, yt);
        yt = fmaf(Ash[13 * 17 + t2], v3.y, yt); yt = fmaf(Ash[14 * 17 + t2], v3.z, yt);
        yt = fmaf(Ash[15 * 17 + t2], v3.w, yt);

        Ysh[ss * 36 + ci] = ys + yt;
    }
    __syncthreads();

    // phase C: 64c x 16ss outputs, 4 per thread; c = k*16 + cg4
    int ss  = tid & 15;
    int cg4 = tid >> 4;
    int s   = sc * 16 + ss;

    float acc[4];
    #pragma unroll
    for (int k = 0; k < 4; ++k) acc[k] = bw[k * 16 + cg4];

    #pragma unroll
    for (int cb = 0; cb < 32; cb += 4) {
        float4 y4 = *(const float4*)&Ysh[ss * 36 + cb];
        #pragma unroll
        for (int k = 0; k < 4; ++k) {
            float4 w4 = *(const float4*)&Wsh[(k * 16 + cg4) * 36 + cb];
            acc[k] = fmaf(w4.x, y4.x, acc[k]);
            acc[k] = fmaf(w4.y, y4.y, acc[k]);
            acc[k] = fmaf(w4.z, y4.z, acc[k]);
            acc[k] = fmaf(w4.w, y4.w, acc[k]);
        }
    }

    #pragma unroll
    for (int k = 0; k < 4; ++k) {
        int c = k * 16 + cg4;
        size_t o = (size_t)b * XB + (size_t)c * S3 + s;
        out[o] = x[o] + acc[k];
    }
}

// ---------------------------------------------------------------------------
extern "C" void kernel_launch(void* const* d_in, const int* in_sizes, int n_in,
                              void* d_out, int out_size, void* d_ws, size_t ws_size,
                              hipStream_t stream)
{
    const float* x   = (const float*)d_in[0];
    const float* Wqs = (const float*)d_in[1];  const float* bqs = (const float*)d_in[2];
    const float* Wks = (const float*)d_in[3];  const float* bks = (const float*)d_in[4];
    const float* Wvs = (const float*)d_in[5];  const float* bvs = (const float*)d_in[6];
    const float* Wqt = (const float*)d_in[7];  const float* bqt = (const float*)d_in[8];
    const float* Wkt = (const float*)d_in[9];  const float* bkt = (const float*)d_in[10];
    const float* Wvt = (const float*)d_in[11]; const float* bvt = (const float*)d_in[12];
    const float* Ww  = (const float*)d_in[13]; const float* bw  = (const float*)d_in[14];

    // workspace layout (float units); ~4.5 MB
    float* ws = (float*)d_ws;
    int*    cnt = (int*)ws;            // 2 counters (+pad to 4)
    ushort* Qb  = (ushort*)(ws + 4);   // 200704 bf16 = 100352 fl
    ushort* Kb  = (ushort*)(ws + 100356);
    ushort* Vb  = (ushort*)(ws + 200708);
    float* Qt   = ws + 301060;         // 200704
    float* Kt   = ws + 501764;
    float* Vt   = ws + 702468;
    float* Y    = ws + 903172;         // 200704
    float* Gpart = ws + 1103876;       // 2*16*256 = 8192
    float* At    = ws + 1112068;       // 512

    proj_kernel<<<dim3(25, 6, 2), 256, 0, stream>>>(
        x, Wqs, bqs, Wks, bks, Wvs, bvs, Wqt, bqt, Wkt, bkt, Wvt, bvt,
        Qb, Kb, Vb, Qt, Kt, Vt, cnt);

    attn_kernel<<<816, 512, 0, stream>>>(Qb, Kb, Vb, Qt, Kt, Y, Gpart, At, cnt);

    merge_final<<<dim3(196, 2), 256, 0, stream>>>(
        Y, At, Vt, x, Ww, bw, (float*)d_out);
}

// Round 9
// 144.853 us; speedup vs baseline: 1.9322x; 1.0294x over previous
//
#include <hip/hip_runtime.h>
#include <math.h>

// Problem constants (B=2, C=64, CI=32, T=16, H=W=14)
#define S3   3136      // per-channel spatial size = 16*196
#define PB   100352    // per-batch proj elements = 32*3136
#define XB   200704    // per-batch x elements = 64*3136
#define NN   6272      // CI*H*W = spatial attention sequence length

typedef __attribute__((ext_vector_type(8))) short bf16x8;   // 8 bf16 = 4 VGPRs
typedef __attribute__((ext_vector_type(4))) float f32x4;    // MFMA C/D

__device__ inline ushort f2bf(float f) {     // RNE f32 -> bf16
    uint u = __float_as_uint(f);
    return (ushort)((u + 0x7FFFu + ((u >> 16) & 1u)) >> 16);
}

// ---------------------------------------------------------------------------
// Kernel 1: all 6 QKV projections, 2x o-split (verified R4/R7). Also zeroes
// the gram completion counters.
// ---------------------------------------------------------------------------
__global__ __launch_bounds__(256) void proj_kernel(
    const float* __restrict__ x,
    const float* __restrict__ W0, const float* __restrict__ b0,
    const float* __restrict__ W1, const float* __restrict__ b1,
    const float* __restrict__ W2, const float* __restrict__ b2,
    const float* __restrict__ W3, const float* __restrict__ b3,
    const float* __restrict__ W4, const float* __restrict__ b4,
    const float* __restrict__ W5, const float* __restrict__ b5,
    ushort* __restrict__ Qb, ushort* __restrict__ Kb, ushort* __restrict__ Vb,
    float* __restrict__ Qt, float* __restrict__ Kt, float* __restrict__ Vt,
    int* __restrict__ cnt)
{
    if (blockIdx.x == 0 && blockIdx.y == 0 && blockIdx.z == 0 && threadIdx.x < 2)
        cnt[threadIdx.x] = 0;

    const float* Wp; const float* bp;
    switch (blockIdx.y) {
        case 0:  Wp = W0; bp = b0; break;
        case 1:  Wp = W1; bp = b1; break;
        case 2:  Wp = W2; bp = b2; break;
        case 3:  Wp = W3; bp = b3; break;
        case 4:  Wp = W4; bp = b4; break;
        default: Wp = W5; bp = b5; break;
    }
    int z = blockIdx.z;               // o in [z*16, z*16+16)

    int gid = blockIdx.x * 256 + threadIdx.x;
    if (gid >= 2 * S3) return;
    int b = (gid >= S3) ? 1 : 0;
    int s = gid - b * S3;

    float xr[64];
    #pragma unroll
    for (int c = 0; c < 64; ++c) xr[c] = x[(size_t)b * XB + (size_t)c * S3 + s];

    float a[16];
    #pragma unroll
    for (int oo = 0; oo < 16; ++oo) {
        int o = z * 16 + oo;
        float acc = bp[o];
        #pragma unroll
        for (int c = 0; c < 64; ++c) acc = fmaf(Wp[o * 64 + c], xr[c], acc);
        a[oo] = acc;
    }

    if (blockIdx.y < 2) {
        // bf16 transposed [n][16]: o = z*16+2k+h -> t = z*8+k, n = h*S3+s
        const float sc = (blockIdx.y == 0) ? 0.36067376022224085f : 1.0f; // 0.25*log2e
        ushort* ob = (blockIdx.y == 0) ? Qb : Kb;
        #pragma unroll
        for (int h = 0; h < 2; ++h) {
            int n = h * S3 + s;
            uint u0 = f2bf(a[0 + h] * sc)  | ((uint)f2bf(a[2 + h]  * sc) << 16);
            uint u1 = f2bf(a[4 + h] * sc)  | ((uint)f2bf(a[6 + h]  * sc) << 16);
            uint u2 = f2bf(a[8 + h] * sc)  | ((uint)f2bf(a[10 + h] * sc) << 16);
            uint u3 = f2bf(a[12 + h] * sc) | ((uint)f2bf(a[14 + h] * sc) << 16);
            *(uint4*)(ob + ((size_t)(b * NN + n) * 16 + z * 8)) = make_uint4(u0, u1, u2, u3);
        }
    } else if (blockIdx.y == 2) {
        // bf16 natural [t][n]
        #pragma unroll
        for (int oo = 0; oo < 16; ++oo) {
            int o = z * 16 + oo;
            Vb[(size_t)(b * 16 + (o >> 1)) * NN + (o & 1) * S3 + s] = f2bf(a[oo]);
        }
    } else {
        float* op = (blockIdx.y == 3) ? Qt : (blockIdx.y == 4) ? Kt : Vt;
        #pragma unroll
        for (int oo = 0; oo < 16; ++oo)
            op[(size_t)b * PB + (size_t)(z * 16 + oo) * S3 + s] = a[oo];
    }
}

// ---------------------------------------------------------------------------
// Kernel 2 (heterogeneous, 816 blocks x 256 threads):
//  blocks 0..783: spatial flash attention, one n-tile per block, 4 waves
//    each covering 1568 m = 12 groups of 128 m + 1 plain 32-m iter.
//    Within a group: all loads first, 8 independent S-MFMAs + exp + pack +
//    8 ds_writes (4 per-wave buffers), then 4 ds_reads + 8 PV-MFMAs.
//    In-block LDS merge -> Y directly.
//  blocks 784..815: temporal Gram partials (392-n chunks); last-arriving
//    block per batch reduces + softmax -> At (atomic counter, verified R7).
// ---------------------------------------------------------------------------
__global__ __launch_bounds__(256, 4) void attn_kernel(
    const ushort* __restrict__ Qb, const ushort* __restrict__ Kb,
    const ushort* __restrict__ Vb, const float* __restrict__ Qt,
    const float* __restrict__ Kt,
    float* __restrict__ Y, float* __restrict__ Gpart,
    float* __restrict__ At, int* __restrict__ cnt)
{
    __shared__ __align__(16) char smem[25600];
    const int tid = threadIdx.x;
    const int bid = blockIdx.x;

    if (bid < 784) {
        // ------------------- spatial flash attention -------------------
        ushort* ptile = (ushort*)smem;                 // 4 waves x 4 bufs x 640 ushorts
        float*  smY   = (float*)(smem + 20480);        // [4][16][17] = 4352 B
        float*  sml   = (float*)(smem + 24832);        // [4][16]     = 256 B

        int wave = __builtin_amdgcn_readfirstlane((int)(tid >> 6));
        int lane = tid & 63;
        int col  = lane & 15;
        int kg   = lane >> 4;
        int b    = (bid >= 392) ? 1 : 0;
        int ntile = bid - b * 392;
        int nbase = ntile * 16;
        int m0    = wave * 1568;

        bf16x8 qf = {0, 0, 0, 0, 0, 0, 0, 0};
        if (kg < 2)
            qf = *(const bf16x8*)(Qb + ((size_t)(b * NN + nbase + col) * 16 + kg * 8));

        const bf16x8 ones = {16256, 16256, 16256, 16256, 16256, 16256, 16256, 16256};
        f32x4 zero4 = {0.f, 0.f, 0.f, 0.f};
        f32x4 yacc  = zero4;
        f32x4 lacc  = zero4;

        ushort* myt = ptile + wave * 2560;             // 4 buffers of 640 ushorts

        const ushort* Vrow = Vb + ((size_t)(b * 16 + col) * NN);
        const ushort* Krow = Kb + ((size_t)b * NN) * 16;

        // ---- 12 groups of 128 m ----
        for (int g = 0; g < 12; ++g) {
            int mb0 = m0 + g * 128;

            // issue ALL loads for the group up front (12 outstanding vmem)
            bf16x8 vf[4];
            #pragma unroll
            for (int i = 0; i < 4; ++i)
                vf[i] = *(const bf16x8*)(Vrow + mb0 + i * 32 + kg * 8);
            bf16x8 kf[8];
            #pragma unroll
            for (int i = 0; i < 8; ++i) {
                bf16x8 kz = {0, 0, 0, 0, 0, 0, 0, 0};
                if (kg < 2)
                    kz = *(const bf16x8*)(Krow + (size_t)(mb0 + i * 16 + col) * 16 + kg * 8);
                kf[i] = kz;
            }

            // S phase: 8 independent MFMAs + exp + pack + ds_write
            #pragma unroll
            for (int i = 0; i < 8; ++i) {
                f32x4 st = __builtin_amdgcn_mfma_f32_16x16x32_bf16(kf[i], qf, zero4, 0, 0, 0);
                float p0 = __builtin_amdgcn_exp2f(st[0]);
                float p1 = __builtin_amdgcn_exp2f(st[1]);
                float p2 = __builtin_amdgcn_exp2f(st[2]);
                float p3 = __builtin_amdgcn_exp2f(st[3]);
                // truncation pack (P >= 0, relative error < 2^-8)
                uint lo = (__float_as_uint(p0) >> 16) | (__float_as_uint(p1) & 0xFFFF0000u);
                uint hi = (__float_as_uint(p2) >> 16) | (__float_as_uint(p3) & 0xFFFF0000u);
                ushort* buf = myt + (i >> 1) * 640;
                *(uint2*)(buf + (col * 40 + (i & 1) * 16 + kg * 4)) = make_uint2(lo, hi);
            }

            // PV phase: 4 reads + 8 MFMAs
            #pragma unroll
            for (int i = 0; i < 4; ++i) {
                bf16x8 pf = *(bf16x8*)(myt + i * 640 + (col * 40 + kg * 8));
                yacc = __builtin_amdgcn_mfma_f32_16x16x32_bf16(vf[i], pf, yacc, 0, 0, 0);
                lacc = __builtin_amdgcn_mfma_f32_16x16x32_bf16(ones, pf, lacc, 0, 0, 0);
            }
        }

        // ---- final plain 32-m iter (m = m0+1536 .. m0+1567) ----
        {
            int mb = m0 + 1536;
            bf16x8 vf = *(const bf16x8*)(Vrow + mb + kg * 8);
            #pragma unroll
            for (int tile = 0; tile < 2; ++tile) {
                int mt = mb + tile * 16;
                bf16x8 kz = {0, 0, 0, 0, 0, 0, 0, 0};
                if (kg < 2)
                    kz = *(const bf16x8*)(Krow + (size_t)(mt + col) * 16 + kg * 8);
                f32x4 st = __builtin_amdgcn_mfma_f32_16x16x32_bf16(kz, qf, zero4, 0, 0, 0);
                float p0 = __builtin_amdgcn_exp2f(st[0]);
                float p1 = __builtin_amdgcn_exp2f(st[1]);
                float p2 = __builtin_amdgcn_exp2f(st[2]);
                float p3 = __builtin_amdgcn_exp2f(st[3]);
                uint lo = (__float_as_uint(p0) >> 16) | (__float_as_uint(p1) & 0xFFFF0000u);
                uint hi = (__float_as_uint(p2) >> 16) | (__float_as_uint(p3) & 0xFFFF0000u);
                *(uint2*)(myt + (col * 40 + tile * 16 + kg * 4)) = make_uint2(lo, hi);
            }
            bf16x8 pf = *(bf16x8*)(myt + (col * 40 + kg * 8));
            yacc = __builtin_amdgcn_mfma_f32_16x16x32_bf16(vf, pf, yacc, 0, 0, 0);
            lacc = __builtin_amdgcn_mfma_f32_16x16x32_bf16(ones, pf, lacc, 0, 0, 0);
        }

        // in-block merge of the 4 m-chunk partials
        #pragma unroll
        for (int r = 0; r < 4; ++r)
            smY[(wave * 16 + kg * 4 + r) * 17 + col] = yacc[r];
        if (kg == 0) sml[wave * 16 + col] = lacc[0];
        __syncthreads();

        int t  = tid >> 4;
        int nn = tid & 15;
        float a = smY[(0 * 16 + t) * 17 + nn] + smY[(1 * 16 + t) * 17 + nn]
                + smY[(2 * 16 + t) * 17 + nn] + smY[(3 * 16 + t) * 17 + nn];
        float l = sml[0 * 16 + nn] + sml[1 * 16 + nn]
                + sml[2 * 16 + nn] + sml[3 * 16 + nn];
        Y[(size_t)b * PB + (size_t)t * NN + nbase + nn] = a / l;
    } else {
        // ------------------- temporal Gram + last-block softmax -------------------
        float* qs = (float*)smem;                      // 1568 floats
        float* ks = qs + 1568;
        int*   flag = (int*)(smem + 25344);

        int gb = bid - 784;                            // 0..31
        int b  = gb >> 4;
        int ch = gb & 15;                              // 392-n chunk
        int t  = tid >> 4, s2 = tid & 15;

        float acc = 0.0f;
        for (int sub = 0; sub < 4; ++sub) {
            size_t base = (size_t)b * PB + (size_t)(ch * 392 + sub * 98) * 16;
            __syncthreads();
            for (int i = tid; i < 392; i += 256) {     // 392 float4 = 1568 floats
                ((float4*)qs)[i] = ((const float4*)(Qt + base))[i];
                ((float4*)ks)[i] = ((const float4*)(Kt + base))[i];
            }
            __syncthreads();
            #pragma unroll 7
            for (int n = 0; n < 98; ++n)
                acc = fmaf(qs[n * 16 + t], ks[n * 16 + s2], acc);
        }
        Gpart[(size_t)(b * 16 + ch) * 256 + tid] = acc;

        __threadfence();                               // release partial
        __syncthreads();
        if (tid == 0) {
            int old = atomicAdd(cnt + b, 1);           // device-scope
            *flag = (old == 15);
        }
        __syncthreads();
        if (*flag) {
            __threadfence();                           // acquire others' partials
            float a = 0.0f;
            #pragma unroll
            for (int c = 0; c < 16; ++c)
                a += Gpart[(size_t)(b * 16 + c) * 256 + tid];
            qs[tid] = a * 0.25f;                       // logits
            __syncthreads();
            if (tid < 16) {
                const float* Lr = &qs[tid * 16];
                float mx = -1e30f;
                #pragma unroll
                for (int s = 0; s < 16; ++s) mx = fmaxf(mx, Lr[s]);
                float e[16]; float sm = 0.0f;
                #pragma unroll
                for (int s = 0; s < 16; ++s) { e[s] = __expf(Lr[s] - mx); sm += e[s]; }
                float inv = 1.0f / sm;
                #pragma unroll
                for (int s = 0; s < 16; ++s) At[b * 256 + tid * 16 + s] = e[s] * inv;
            }
        }
    }
}

// ---------------------------------------------------------------------------
// Kernel 3: yt add + output projection + residual. Grid (196, 2). (verified R7)
// ---------------------------------------------------------------------------
__global__ __launch_bounds__(256) void merge_final(
    const float* __restrict__ Y, const float* __restrict__ At,
    const float* __restrict__ Vt, const float* __restrict__ x,
    const float* __restrict__ Ww, const float* __restrict__ bw,
    float* __restrict__ out)
{
    __shared__ float Ash[16 * 17];   // [s2][t2]
    __shared__ float Wsh[64 * 36];   // [c][ci]
    __shared__ float Ysh[16 * 36];   // [ss][ci]

    int b  = blockIdx.y;
    int sc = blockIdx.x;             // s chunk [sc*16, sc*16+16)
    int tid = threadIdx.x;

    {
        int s2 = tid >> 4, t2 = tid & 15;
        Ash[s2 * 17 + t2] = At[b * 256 + t2 * 16 + s2];
        for (int i = tid; i < 2048; i += 256)
            Wsh[(i >> 5) * 36 + (i & 31)] = Ww[i];
    }
    __syncthreads();

    // phase B: 512 Y values, 2 per thread
    #pragma unroll
    for (int k = 0; k < 2; ++k) {
        int idx = tid + k * 256;
        int ss = idx & 15;
        int ci = idx >> 4;                     // 0..31
        int s  = sc * 16 + ss;
        int t  = ci >> 1;
        int nn = (ci & 1) * S3 + s;

        float ys = Y[(size_t)b * PB + (size_t)ci * S3 + s];

        int t2 = nn & 15;
        const float4* vp = (const float4*)(Vt + (size_t)b * PB + (size_t)t * NN + (nn & ~15));
        float4 v0 = vp[0], v1 = vp[1], v2 = vp[2], v3 = vp[3];
        float yt = Ash[0 * 17 + t2] * v0.x;
        yt = fmaf(Ash[1 * 17 + t2],  v0.y, yt); yt = fmaf(Ash[2 * 17 + t2],  v0.z, yt);
        yt = fmaf(Ash[3 * 17 + t2],  v0.w, yt); yt = fmaf(Ash[4 * 17 + t2],  v1.x, yt);
        yt = fmaf(Ash[5 * 17 + t2],  v1.y, yt); yt = fmaf(Ash[6 * 17 + t2],  v1.z, yt);
        yt = fmaf(Ash[7 * 17 + t2],  v1.w, yt); yt = fmaf(Ash[8 * 17 + t2],  v2.x, yt);
        yt = fmaf(Ash[9 * 17 + t2],  v2.y, yt); yt = fmaf(Ash[10 * 17 + t2], v2.z, yt);
        yt = fmaf(Ash[11 * 17 + t2], v2.w, yt); yt = fmaf(Ash[12 * 17 + t2], v3.x, yt);
        yt = fmaf(Ash[13 * 17 + t2], v3.y, yt); yt = fmaf(Ash[14 * 17 + t2], v3.z, yt);
        yt = fmaf(Ash[15 * 17 + t2], v3.w, yt);

        Ysh[ss * 36 + ci] = ys + yt;
    }
    __syncthreads();

    // phase C: 64c x 16ss outputs, 4 per thread; c = k*16 + cg4
    int ss  = tid & 15;
    int cg4 = tid >> 4;
    int s   = sc * 16 + ss;

    float acc[4];
    #pragma unroll
    for (int k = 0; k < 4; ++k) acc[k] = bw[k * 16 + cg4];

    #pragma unroll
    for (int cb = 0; cb < 32; cb += 4) {
        float4 y4 = *(const float4*)&Ysh[ss * 36 + cb];
        #pragma unroll
        for (int k = 0; k < 4; ++k) {
            float4 w4 = *(const float4*)&Wsh[(k * 16 + cg4) * 36 + cb];
            acc[k] = fmaf(w4.x, y4.x, acc[k]);
            acc[k] = fmaf(w4.y, y4.y, acc[k]);
            acc[k] = fmaf(w4.z, y4.z, acc[k]);
            acc[k] = fmaf(w4.w, y4.w, acc[k]);
        }
    }

    #pragma unroll
    for (int k = 0; k < 4; ++k) {
        int c = k * 16 + cg4;
        size_t o = (size_t)b * XB + (size_t)c * S3 + s;
        out[o] = x[o] + acc[k];
    }
}

// ---------------------------------------------------------------------------
extern "C" void kernel_launch(void* const* d_in, const int* in_sizes, int n_in,
                              void* d_out, int out_size, void* d_ws, size_t ws_size,
                              hipStream_t stream)
{
    const float* x   = (const float*)d_in[0];
    const float* Wqs = (const float*)d_in[1];  const float* bqs = (const float*)d_in[2];
    const float* Wks = (const float*)d_in[3];  const float* bks = (const float*)d_in[4];
    const float* Wvs = (const float*)d_in[5];  const float* bvs = (const float*)d_in[6];
    const float* Wqt = (const float*)d_in[7];  const float* bqt = (const float*)d_in[8];
    const float* Wkt = (const float*)d_in[9];  const float* bkt = (const float*)d_in[10];
    const float* Wvt = (const float*)d_in[11]; const float* bvt = (const float*)d_in[12];
    const float* Ww  = (const float*)d_in[13]; const float* bw  = (const float*)d_in[14];

    // workspace layout (float units); ~4.5 MB
    float* ws = (float*)d_ws;
    int*    cnt = (int*)ws;            // 2 counters (+pad to 4)
    ushort* Qb  = (ushort*)(ws + 4);   // 200704 bf16 = 100352 fl
    ushort* Kb  = (ushort*)(ws + 100356);
    ushort* Vb  = (ushort*)(ws + 200708);
    float* Qt   = ws + 301060;         // 200704
    float* Kt   = ws + 501764;
    float* Vt   = ws + 702468;
    float* Y    = ws + 903172;         // 200704
    float* Gpart = ws + 1103876;       // 2*16*256 = 8192
    float* At    = ws + 1112068;       // 512

    proj_kernel<<<dim3(25, 6, 2), 256, 0, stream>>>(
        x, Wqs, bqs, Wks, bks, Wvs, bvs, Wqt, bqt, Wkt, bkt, Wvt, bvt,
        Qb, Kb, Vb, Qt, Kt, Vt, cnt);

    attn_kernel<<<816, 256, 0, stream>>>(Qb, Kb, Vb, Qt, Kt, Y, Gpart, At, cnt);

    merge_final<<<dim3(196, 2), 256, 0, stream>>>(
        Y, At, Vt, x, Ww, bw, (float*)d_out);
}